// Round 7
// baseline (212.283 us; speedup 1.0000x reference)
//
#include <hip/hip_runtime.h>

#define N_NODES 10000
#define N_EDGES 160000
#define NC 8
#define LN_EPS 1e-5f

typedef _Float16 h4_t __attribute__((ext_vector_type(4)));
typedef _Float16 h8_t __attribute__((ext_vector_type(8)));

// Conflict-free LDS transpose swizzle for a 64x64 fp32 tile.
__device__ __forceinline__ int swz(int e, int b) {
  return e * 64 + ((((b >> 2) ^ ((e >> 2) & 15)) << 2) | (b & 3));
}

// ---------------- K1: histogram of dst and src ----------------
__global__ void hist_kernel(const int* __restrict__ edst, const int* __restrict__ esrc,
                            int* __restrict__ cnt_dst, int* __restrict__ cnt_src) {
  const int e = blockIdx.x * 256 + threadIdx.x;
  if (e < N_EDGES) {
    atomicAdd(&cnt_dst[edst[e]], 1);
    atomicAdd(&cnt_src[esrc[e]], 1);
  }
}

// ---------------- K2: exclusive scan (block 0: dst, block 1: src) -------------
__global__ void __launch_bounds__(1024) scan_kernel(
    const int* __restrict__ cnt_dst, const int* __restrict__ cnt_src,
    int* __restrict__ start_dst, int* __restrict__ cur_dst,
    int* __restrict__ start_src, int* __restrict__ cur_src) {
  const int* cnt = blockIdx.x ? cnt_src : cnt_dst;
  int* start = blockIdx.x ? start_src : start_dst;
  int* cur   = blockIdx.x ? cur_src   : cur_dst;

  const int t = threadIdx.x;
  const int lane = t & 63;
  const int wid = t >> 6;                 // 0..15
  const int lo = t * 10;
  const int hi = min(lo + 10, N_NODES);
  int s = 0;
  for (int i = lo; i < hi; ++i) s += cnt[i];
  const int own = s;
#pragma unroll
  for (int d = 1; d < 64; d <<= 1) {
    const int v = __shfl_up(s, d, 64);
    if (lane >= d) s += v;
  }
  __shared__ int wsum[16];
  if (lane == 63) wsum[wid] = s;
  __syncthreads();
  if (t == 0) {
    int acc = 0;
#pragma unroll
    for (int i = 0; i < 16; ++i) { acc += wsum[i]; wsum[i] = acc; }
  }
  __syncthreads();
  int base = (wid ? wsum[wid - 1] : 0) + s - own;
  for (int i = lo; i < hi; ++i) {
    start[i] = base;
    cur[i] = base;
    base += cnt[i];
  }
  if (t == 1023) start[N_NODES] = base;   // == N_EDGES
}

// ---------------- K3: prep — sort EVERYTHING node_kernel reads ---------------
// Edge e, dst-rank p, src-rank q:
//   xT_d[p][b] = (fp16)x[b][e]   (128 B line-exact scatter)
//   w1_s[p]    = w1[e]           (32 B scatter, ~4x write amp — cheap)
//   w3_s[q]    = w3[e]
//   sorted_src[q] = e            (only used as WRITE addresses in node)
__global__ void __launch_bounds__(256) prep_kernel(
    const float* __restrict__ x, const int* __restrict__ edst,
    const int* __restrict__ esrc, const float* __restrict__ w1,
    const float* __restrict__ w3, int* __restrict__ cur_dst,
    int* __restrict__ cur_src, _Float16* __restrict__ xT_d,
    float* __restrict__ w1_s, float* __restrict__ w3_s,
    int* __restrict__ sorted_src) {
  __shared__ float tile[64 * 64];
  __shared__ int pP[64];
  const int e0 = blockIdx.x * 64;
  const int t = threadIdx.x;

  if (t < 64) {
    const int e = e0 + t;
    const int p = atomicAdd(&cur_dst[edst[e]], 1);
    pP[t] = p;
    const int q = atomicAdd(&cur_src[esrc[e]], 1);
    sorted_src[q] = e;
    const float4* wp1 = (const float4*)(w1 + (size_t)e * NC);
    float4* dp1 = (float4*)(w1_s + (size_t)p * NC);
    dp1[0] = wp1[0]; dp1[1] = wp1[1];
    const float4* wp3 = (const float4*)(w3 + (size_t)e * NC);
    float4* dp3 = (float4*)(w3_s + (size_t)q * NC);
    dp3[0] = wp3[0]; dp3[1] = wp3[1];
  }

  const int u = t & 15;
  const int row = t >> 4;                 // 0..15
#pragma unroll
  for (int j = 0; j < 4; ++j) {           // read x rows (b), float4 over e
    const int b = j * 16 + row;
    const float4 xv = *(const float4*)&x[(size_t)b * N_EDGES + e0 + 4 * u];
    tile[swz(4 * u + 0, b)] = xv.x;
    tile[swz(4 * u + 1, b)] = xv.y;
    tile[swz(4 * u + 2, b)] = xv.z;
    tile[swz(4 * u + 3, b)] = xv.w;
  }
  __syncthreads();
#pragma unroll
  for (int j = 0; j < 4; ++j) {           // write sorted fp16 row: half4 over b
    const int r = j * 16 + row;
    const float4 vv = *(const float4*)&tile[r * 64 + ((u ^ ((r >> 2) & 15)) << 2)];
    h4_t hv;
    hv[0] = (_Float16)vv.x; hv[1] = (_Float16)vv.y;
    hv[2] = (_Float16)vv.z; hv[3] = (_Float16)vv.w;
    *(h4_t*)&xT_d[(size_t)pP[r] * 64 + 4 * u] = hv;
  }
}

// ---------------- K4: segment-sum + LN + ELU + src-side dot -> outT (fp16) ----
// 4 nodes/block, lane = b. ALL reads are sequential affine streams; the only
// indirect address is the outT store (fire-and-forget, 128B line-exact).
__global__ void __launch_bounds__(256) node_kernel(
    const _Float16* __restrict__ xT_d, const float* __restrict__ w1_s,
    const float* __restrict__ b1, const float* __restrict__ gamma,
    const float* __restrict__ beta, const int* __restrict__ start_dst,
    const int* __restrict__ sorted_src, const int* __restrict__ start_src,
    const float* __restrict__ w3_s, _Float16* __restrict__ outT) {
  const int n = blockIdx.x * 4 + (threadIdx.x >> 6);
  const int b = threadIdx.x & 63;

  float a[NC];
#pragma unroll
  for (int c = 0; c < NC; ++c) a[c] = 0.f;

  const int s0 = start_dst[n];
  const int s1 = start_dst[n + 1];
  int i = s0;
  for (; i + 4 <= s1; i += 4) {
    float xe[4];
#pragma unroll
    for (int k = 0; k < 4; ++k) xe[k] = (float)xT_d[(size_t)(i + k) * 64 + b];
    float4 wla[4], wlb[4];
#pragma unroll
    for (int k = 0; k < 4; ++k) {
      const float4* wp = (const float4*)(w1_s + (size_t)(i + k) * NC);
      wla[k] = wp[0]; wlb[k] = wp[1];
    }
#pragma unroll
    for (int k = 0; k < 4; ++k) {
      a[0] += xe[k] * wla[k].x; a[1] += xe[k] * wla[k].y;
      a[2] += xe[k] * wla[k].z; a[3] += xe[k] * wla[k].w;
      a[4] += xe[k] * wlb[k].x; a[5] += xe[k] * wlb[k].y;
      a[6] += xe[k] * wlb[k].z; a[7] += xe[k] * wlb[k].w;
    }
  }
  for (; i < s1; ++i) {
    const float xe = (float)xT_d[(size_t)i * 64 + b];
    const float4* wp = (const float4*)(w1_s + (size_t)i * NC);
    const float4 wa = wp[0], wb = wp[1];
    a[0] += xe * wa.x; a[1] += xe * wa.y; a[2] += xe * wa.z; a[3] += xe * wa.w;
    a[4] += xe * wb.x; a[5] += xe * wb.y; a[6] += xe * wb.z; a[7] += xe * wb.w;
  }

  const float4* b1p = (const float4*)(b1 + (size_t)n * NC);
  const float4 b1a = b1p[0], b1b = b1p[1];
  a[0] += b1a.x; a[1] += b1a.y; a[2] += b1a.z; a[3] += b1a.w;
  a[4] += b1b.x; a[5] += b1b.y; a[6] += b1b.z; a[7] += b1b.w;

  float mu = 0.f;
#pragma unroll
  for (int c = 0; c < NC; ++c) mu += a[c];
  mu *= 0.125f;
  float var = 0.f;
#pragma unroll
  for (int c = 0; c < NC; ++c) { a[c] -= mu; var += a[c] * a[c]; }
  var *= 0.125f;
  const float rs = rsqrtf(var + LN_EPS);

  const float4* gp = (const float4*)(gamma + (size_t)n * NC);
  const float4 ga = gp[0], gb = gp[1];
  const float4* bp = (const float4*)(beta + (size_t)n * NC);
  const float4 ba = bp[0], bb = bp[1];
  float w[NC];
  w[0] = a[0] * rs * ga.x + ba.x;  w[1] = a[1] * rs * ga.y + ba.y;
  w[2] = a[2] * rs * ga.z + ba.z;  w[3] = a[3] * rs * ga.w + ba.w;
  w[4] = a[4] * rs * gb.x + bb.x;  w[5] = a[5] * rs * gb.y + bb.y;
  w[6] = a[6] * rs * gb.z + bb.z;  w[7] = a[7] * rs * gb.w + bb.w;
#pragma unroll
  for (int c = 0; c < NC; ++c) w[c] = w[c] > 0.f ? w[c] : expm1f(w[c]);

  // src-side: w3_s + sorted_src both sequential; 128B fp16 scatter store.
  const int t0 = start_src[n];
  const int t1 = start_src[n + 1];
  int j = t0;
  for (; j + 4 <= t1; j += 4) {
    int ee[4];
#pragma unroll
    for (int k = 0; k < 4; ++k) ee[k] = sorted_src[j + k];
    float4 wla[4], wlb[4];
#pragma unroll
    for (int k = 0; k < 4; ++k) {
      const float4* wp = (const float4*)(w3_s + (size_t)(j + k) * NC);
      wla[k] = wp[0]; wlb[k] = wp[1];
    }
#pragma unroll
    for (int k = 0; k < 4; ++k) {
      const float dot = w[0] * wla[k].x + w[1] * wla[k].y + w[2] * wla[k].z + w[3] * wla[k].w +
                        w[4] * wlb[k].x + w[5] * wlb[k].y + w[6] * wlb[k].z + w[7] * wlb[k].w;
      outT[(size_t)ee[k] * 64 + b] = (_Float16)dot;
    }
  }
  for (; j < t1; ++j) {
    const int e = sorted_src[j];
    const float4* wp = (const float4*)(w3_s + (size_t)j * NC);
    const float4 wa = wp[0], wb = wp[1];
    const float dot = w[0] * wa.x + w[1] * wa.y + w[2] * wa.z + w[3] * wa.w +
                      w[4] * wb.x + w[5] * wb.y + w[6] * wb.z + w[7] * wb.w;
    outT[(size_t)e * 64 + b] = (_Float16)dot;
  }
}

// ---------------- K5: finalize — transpose outT (E,B fp16) -> out (B,E), +b3+x
__global__ void __launch_bounds__(256) finalize_kernel(
    const _Float16* __restrict__ outT, const float* __restrict__ b3,
    const float* __restrict__ x, float* __restrict__ out) {
  __shared__ float tile[64 * 64];
  const int e0 = blockIdx.x * 64;
  const int t = threadIdx.x;
  const int u = t & 15;
  const int row = t >> 4;                 // 0..15
#pragma unroll
  for (int j = 0; j < 4; ++j) {           // read outT rows (e), h4 over b
    const int e = j * 16 + row;
    const h4_t hv = *(const h4_t*)&outT[(size_t)(e0 + e) * 64 + 4 * u];
    float4 fv;
    fv.x = (float)hv[0]; fv.y = (float)hv[1];
    fv.z = (float)hv[2]; fv.w = (float)hv[3];
    *(float4*)&tile[e * 64 + ((u ^ ((e >> 2) & 15)) << 2)] = fv;
  }
  __syncthreads();
  const float4 bb = *(const float4*)&b3[e0 + 4 * u];
#pragma unroll
  for (int j = 0; j < 4; ++j) {           // write out rows (b), float4 over e
    const int bo = j * 16 + row;
    const float o0 = tile[swz(4 * u + 0, bo)];
    const float o1 = tile[swz(4 * u + 1, bo)];
    const float o2 = tile[swz(4 * u + 2, bo)];
    const float o3 = tile[swz(4 * u + 3, bo)];
    const float4 xb = *(const float4*)&x[(size_t)bo * N_EDGES + e0 + 4 * u];
    float4 o;
    o.x = o0 + bb.x + xb.x;  o.y = o1 + bb.y + xb.y;
    o.z = o2 + bb.z + xb.z;  o.w = o3 + bb.w + xb.w;
    *(float4*)&out[(size_t)bo * N_EDGES + e0 + 4 * u] = o;
  }
}

extern "C" void kernel_launch(void* const* d_in, const int* in_sizes, int n_in,
                              void* d_out, int out_size, void* d_ws, size_t ws_size,
                              hipStream_t stream) {
  const float* x     = (const float*)d_in[0];
  const float* w1    = (const float*)d_in[1];
  const float* b1    = (const float*)d_in[2];
  const float* gamma = (const float*)d_in[3];
  const float* beta  = (const float*)d_in[4];
  const float* w3    = (const float*)d_in[5];
  const float* b3    = (const float*)d_in[6];
  const int* esrc    = (const int*)d_in[7];
  const int* edst    = (const int*)d_in[8];
  float* out = (float*)d_out;

  char* ws = (char*)d_ws;
  size_t off = 0;
  auto alloc = [&](size_t bytes) -> void* {
    void* p = ws + off;
    off += (bytes + 255) & ~(size_t)255;
    return p;
  };
  _Float16* xT_d   = (_Float16*)alloc((size_t)N_EDGES * 64 * 2);
  _Float16* outT   = (_Float16*)alloc((size_t)N_EDGES * 64 * 2);
  float* w1_s      = (float*)alloc((size_t)N_EDGES * NC * 4);
  float* w3_s      = (float*)alloc((size_t)N_EDGES * NC * 4);
  int* sorted_src  = (int*)alloc((size_t)N_EDGES * 4);
  int* cnt_dst     = (int*)alloc((size_t)N_NODES * 4);
  int* cnt_src     = (int*)alloc((size_t)N_NODES * 4);
  int* start_dst   = (int*)alloc((size_t)(N_NODES + 1) * 4);
  int* start_src   = (int*)alloc((size_t)(N_NODES + 1) * 4);
  int* cur_dst     = (int*)alloc((size_t)N_NODES * 4);
  int* cur_src     = (int*)alloc((size_t)N_NODES * 4);

  // zero both histograms (adjacent in ws; pad gap is harmless)
  hipMemsetAsync(cnt_dst, 0, (size_t)2 * N_NODES * 4 + 512, stream);

  hist_kernel<<<N_EDGES / 256, 256, 0, stream>>>(edst, esrc, cnt_dst, cnt_src);
  scan_kernel<<<2, 1024, 0, stream>>>(cnt_dst, cnt_src, start_dst, cur_dst,
                                      start_src, cur_src);
  prep_kernel<<<N_EDGES / 64, 256, 0, stream>>>(x, edst, esrc, w1, w3,
                                                cur_dst, cur_src, xT_d,
                                                w1_s, w3_s, sorted_src);
  node_kernel<<<N_NODES / 4, 256, 0, stream>>>(xT_d, w1_s, b1, gamma, beta,
                                               start_dst, sorted_src, start_src,
                                               w3_s, outT);
  finalize_kernel<<<N_EDGES / 64, 256, 0, stream>>>(outT, b3, x, out);
}

// Round 8
// 188.357 us; speedup vs baseline: 1.1270x; 1.1270x over previous
//
#include <hip/hip_runtime.h>

#define N_NODES 10000
#define N_EDGES 160000
#define NC 8
#define LN_EPS 1e-5f

typedef _Float16 h4_t __attribute__((ext_vector_type(4)));
typedef _Float16 h8_t __attribute__((ext_vector_type(8)));

// Conflict-free LDS transpose swizzle for a 64x64 fp32 tile.
__device__ __forceinline__ int swz(int e, int b) {
  return e * 64 + ((((b >> 2) ^ ((e >> 2) & 15)) << 2) | (b & 3));
}

// ---------------- K1: histogram of dst ----------------
__global__ void hist_kernel(const int* __restrict__ edst, int* __restrict__ cnt_dst) {
  const int e = blockIdx.x * 256 + threadIdx.x;
  if (e < N_EDGES) atomicAdd(&cnt_dst[edst[e]], 1);
}

// ---------------- K2: exclusive scan over dst counts (1 block) ----------------
__global__ void __launch_bounds__(1024) scan_kernel(
    const int* __restrict__ cnt, int* __restrict__ start, int* __restrict__ cur) {
  const int t = threadIdx.x;
  const int lane = t & 63;
  const int wid = t >> 6;                 // 0..15
  const int lo = t * 10;
  const int hi = min(lo + 10, N_NODES);
  int s = 0;
  for (int i = lo; i < hi; ++i) s += cnt[i];
  const int own = s;
#pragma unroll
  for (int d = 1; d < 64; d <<= 1) {
    const int v = __shfl_up(s, d, 64);
    if (lane >= d) s += v;
  }
  __shared__ int wsum[16];
  if (lane == 63) wsum[wid] = s;
  __syncthreads();
  if (t == 0) {
    int acc = 0;
#pragma unroll
    for (int i = 0; i < 16; ++i) { acc += wsum[i]; wsum[i] = acc; }
  }
  __syncthreads();
  int base = (wid ? wsum[wid - 1] : 0) + s - own;
  for (int i = lo; i < hi; ++i) {
    start[i] = base;
    cur[i] = base;
    base += cnt[i];
  }
  if (t == 1023) start[N_NODES] = base;   // == N_EDGES
}

// ---------------- K3: prep — dst-sort x rows (fp16) + w1 rows (fp16) ----------
// Edge e with dst-rank p:
//   xT_d[p][b] = (fp16)x[b][e]   (128 B line-exact scatter)
//   w1_h[p][c] = (fp16)w1[e][c]  (16 B scatter — replaces sorted_dst ids)
// node_kernel then has ZERO read indirection.
__global__ void __launch_bounds__(256) prep_kernel(
    const float* __restrict__ x, const int* __restrict__ edst,
    const float* __restrict__ w1, int* __restrict__ cur_dst,
    _Float16* __restrict__ xT_d, _Float16* __restrict__ w1_h) {
  __shared__ float tile[64 * 64];
  __shared__ int pP[64];
  const int e0 = blockIdx.x * 64;
  const int t = threadIdx.x;

  if (t < 64) {
    const int e = e0 + t;
    const int p = atomicAdd(&cur_dst[edst[e]], 1);
    pP[t] = p;
    const float4* wp1 = (const float4*)(w1 + (size_t)e * NC);
    const float4 wa = wp1[0], wb = wp1[1];
    h8_t hw;
    hw[0] = (_Float16)wa.x; hw[1] = (_Float16)wa.y;
    hw[2] = (_Float16)wa.z; hw[3] = (_Float16)wa.w;
    hw[4] = (_Float16)wb.x; hw[5] = (_Float16)wb.y;
    hw[6] = (_Float16)wb.z; hw[7] = (_Float16)wb.w;
    *(h8_t*)&w1_h[(size_t)p * NC] = hw;
  }

  const int u = t & 15;
  const int row = t >> 4;                 // 0..15
#pragma unroll
  for (int j = 0; j < 4; ++j) {           // read x rows (b), float4 over e
    const int b = j * 16 + row;
    const float4 xv = *(const float4*)&x[(size_t)b * N_EDGES + e0 + 4 * u];
    tile[swz(4 * u + 0, b)] = xv.x;
    tile[swz(4 * u + 1, b)] = xv.y;
    tile[swz(4 * u + 2, b)] = xv.z;
    tile[swz(4 * u + 3, b)] = xv.w;
  }
  __syncthreads();
#pragma unroll
  for (int j = 0; j < 4; ++j) {           // write sorted fp16 row: half4 over b
    const int r = j * 16 + row;
    const float4 vv = *(const float4*)&tile[r * 64 + ((u ^ ((r >> 2) & 15)) << 2)];
    h4_t hv;
    hv[0] = (_Float16)vv.x; hv[1] = (_Float16)vv.y;
    hv[2] = (_Float16)vv.z; hv[3] = (_Float16)vv.w;
    *(h4_t*)&xT_d[(size_t)pP[r] * 64 + 4 * u] = hv;
  }
}

// ---------------- K4: segment-sum + LN + ELU -> v[n][b][c] (fp16, sequential) -
// 4 nodes/block, lane = b. ALL accesses are sequential affine streams.
__global__ void __launch_bounds__(256) node_kernel(
    const _Float16* __restrict__ xT_d, const _Float16* __restrict__ w1_h,
    const float* __restrict__ b1, const float* __restrict__ gamma,
    const float* __restrict__ beta, const int* __restrict__ start_dst,
    _Float16* __restrict__ v) {
  const int n = blockIdx.x * 4 + (threadIdx.x >> 6);
  const int b = threadIdx.x & 63;

  float a[NC];
#pragma unroll
  for (int c = 0; c < NC; ++c) a[c] = 0.f;

  const int s0 = start_dst[n];
  const int s1 = start_dst[n + 1];
  int i = s0;
  for (; i + 4 <= s1; i += 4) {
    float xe[4];
#pragma unroll
    for (int k = 0; k < 4; ++k) xe[k] = (float)xT_d[(size_t)(i + k) * 64 + b];
    h8_t wl[4];
#pragma unroll
    for (int k = 0; k < 4; ++k) wl[k] = *(const h8_t*)&w1_h[(size_t)(i + k) * NC];
#pragma unroll
    for (int k = 0; k < 4; ++k) {
#pragma unroll
      for (int c = 0; c < NC; ++c) a[c] += xe[k] * (float)wl[k][c];
    }
  }
  for (; i < s1; ++i) {
    const float xe = (float)xT_d[(size_t)i * 64 + b];
    const h8_t wl = *(const h8_t*)&w1_h[(size_t)i * NC];
#pragma unroll
    for (int c = 0; c < NC; ++c) a[c] += xe * (float)wl[c];
  }

  const float4* b1p = (const float4*)(b1 + (size_t)n * NC);
  const float4 b1a = b1p[0], b1b = b1p[1];
  a[0] += b1a.x; a[1] += b1a.y; a[2] += b1a.z; a[3] += b1a.w;
  a[4] += b1b.x; a[5] += b1b.y; a[6] += b1b.z; a[7] += b1b.w;

  float mu = 0.f;
#pragma unroll
  for (int c = 0; c < NC; ++c) mu += a[c];
  mu *= 0.125f;
  float var = 0.f;
#pragma unroll
  for (int c = 0; c < NC; ++c) { a[c] -= mu; var += a[c] * a[c]; }
  var *= 0.125f;
  const float rs = rsqrtf(var + LN_EPS);

  const float4* gp = (const float4*)(gamma + (size_t)n * NC);
  const float4 ga = gp[0], gb = gp[1];
  const float4* bp = (const float4*)(beta + (size_t)n * NC);
  const float4 ba = bp[0], bb = bp[1];
  float w[NC];
  w[0] = a[0] * rs * ga.x + ba.x;  w[1] = a[1] * rs * ga.y + ba.y;
  w[2] = a[2] * rs * ga.z + ba.z;  w[3] = a[3] * rs * ga.w + ba.w;
  w[4] = a[4] * rs * gb.x + bb.x;  w[5] = a[5] * rs * gb.y + bb.y;
  w[6] = a[6] * rs * gb.z + bb.z;  w[7] = a[7] * rs * gb.w + bb.w;
#pragma unroll
  for (int c = 0; c < NC; ++c) w[c] = w[c] > 0.f ? w[c] : expm1f(w[c]);

  h8_t hv;
#pragma unroll
  for (int c = 0; c < NC; ++c) hv[c] = (_Float16)w[c];
  *(h8_t*)&v[(size_t)n * 512 + b * NC] = hv;     // wave writes 1KB contiguous
}

// ---------------- K5: edge kernel — gather v[src], dot w3, +b3+x -> out -------
// 64 edges/block; 4 waves x 16 edges. All 16 v-row gathers issued before any
// use (64 VGPRs in flight); x/b3 prefetched alongside. LDS transpose ->
// coalesced float4 out writes.
__global__ void __launch_bounds__(256) edge_kernel(
    const _Float16* __restrict__ v, const float* __restrict__ w3,
    const float* __restrict__ b3, const float* __restrict__ x,
    const int* __restrict__ esrc, float* __restrict__ out) {
  __shared__ float tile[64 * 64];
  const int e0 = blockIdx.x * 64;
  const int t = threadIdx.x;
  const int w = t >> 6;                   // wave 0..3 -> edges w*16..w*16+15
  const int b = t & 63;
  const int u = t & 15;
  const int row = t >> 4;                 // 0..15

  int sidx = 0;
  if (b < 16) sidx = esrc[e0 + w * 16 + b];

  // issue all 16 v-row gathers (16B/lane each) before any dependent use
  h8_t hv[16];
#pragma unroll
  for (int r = 0; r < 16; ++r) {
    const int s = __shfl(sidx, r, 64);
    hv[r] = *(const h8_t*)&v[(size_t)s * 512 + b * NC];
  }
  // prefetch the independent final-phase operands while gathers are in flight
  const float4 bb = *(const float4*)&b3[e0 + 4 * u];
  float4 xb[4];
#pragma unroll
  for (int j = 0; j < 4; ++j) {
    const int bo = j * 16 + row;
    xb[j] = *(const float4*)&x[(size_t)bo * N_EDGES + e0 + 4 * u];
  }

#pragma unroll
  for (int r = 0; r < 16; ++r) {
    const float4* wp = (const float4*)(w3 + (size_t)(e0 + w * 16 + r) * NC);
    const float4 wa = wp[0], wb = wp[1];
    const float dot =
        (float)hv[r][0] * wa.x + (float)hv[r][1] * wa.y +
        (float)hv[r][2] * wa.z + (float)hv[r][3] * wa.w +
        (float)hv[r][4] * wb.x + (float)hv[r][5] * wb.y +
        (float)hv[r][6] * wb.z + (float)hv[r][7] * wb.w;
    tile[swz(w * 16 + r, b)] = dot;
  }
  __syncthreads();

#pragma unroll
  for (int j = 0; j < 4; ++j) {
    const int bo = j * 16 + row;
    const float o0 = tile[swz(4 * u + 0, bo)];
    const float o1 = tile[swz(4 * u + 1, bo)];
    const float o2 = tile[swz(4 * u + 2, bo)];
    const float o3 = tile[swz(4 * u + 3, bo)];
    float4 o;
    o.x = o0 + bb.x + xb[j].x;  o.y = o1 + bb.y + xb[j].y;
    o.z = o2 + bb.z + xb[j].z;  o.w = o3 + bb.w + xb[j].w;
    *(float4*)&out[(size_t)bo * N_EDGES + e0 + 4 * u] = o;
  }
}

extern "C" void kernel_launch(void* const* d_in, const int* in_sizes, int n_in,
                              void* d_out, int out_size, void* d_ws, size_t ws_size,
                              hipStream_t stream) {
  const float* x     = (const float*)d_in[0];
  const float* w1    = (const float*)d_in[1];
  const float* b1    = (const float*)d_in[2];
  const float* gamma = (const float*)d_in[3];
  const float* beta  = (const float*)d_in[4];
  const float* w3    = (const float*)d_in[5];
  const float* b3    = (const float*)d_in[6];
  const int* esrc    = (const int*)d_in[7];
  const int* edst    = (const int*)d_in[8];
  float* out = (float*)d_out;

  char* ws = (char*)d_ws;
  size_t off = 0;
  auto alloc = [&](size_t bytes) -> void* {
    void* p = ws + off;
    off += (bytes + 255) & ~(size_t)255;
    return p;
  };
  _Float16* xT_d   = (_Float16*)alloc((size_t)N_EDGES * 64 * 2);
  _Float16* w1_h   = (_Float16*)alloc((size_t)N_EDGES * NC * 2);
  _Float16* v      = (_Float16*)alloc((size_t)N_NODES * 512 * 2);
  int* cnt_dst     = (int*)alloc((size_t)N_NODES * 4);
  int* start_dst   = (int*)alloc((size_t)(N_NODES + 1) * 4);
  int* cur_dst     = (int*)alloc((size_t)N_NODES * 4);

  hipMemsetAsync(cnt_dst, 0, (size_t)N_NODES * 4, stream);

  hist_kernel<<<N_EDGES / 256, 256, 0, stream>>>(edst, cnt_dst);
  scan_kernel<<<1, 1024, 0, stream>>>(cnt_dst, start_dst, cur_dst);
  prep_kernel<<<N_EDGES / 64, 256, 0, stream>>>(x, edst, w1, cur_dst, xT_d, w1_h);
  node_kernel<<<N_NODES / 4, 256, 0, stream>>>(xT_d, w1_h, b1, gamma, beta,
                                               start_dst, v);
  edge_kernel<<<N_EDGES / 64, 256, 0, stream>>>(v, w3, b3, x, esrc, out);
}